// Round 2
// 251.580 us; speedup vs baseline: 1.1783x; 1.1783x over previous
//
#include <hip/hip_runtime.h>

typedef __bf16 bf16;
typedef __bf16 bf16x8 __attribute__((ext_vector_type(8)));
typedef __bf16 bf16x4 __attribute__((ext_vector_type(4)));
typedef float f32x4 __attribute__((ext_vector_type(4)));

#define MFMA(a, b, c) __builtin_amdgcn_mfma_f32_16x16x32_bf16((a), (b), (c), 0, 0, 0)

static __device__ __forceinline__ f32x4 zero4() {
    f32x4 z; z[0] = 0.f; z[1] = 0.f; z[2] = 0.f; z[3] = 0.f; return z;
}

// ---------------- fused prep: all f32->bf16 conversions, one launch ----------------
__global__ __launch_bounds__(256) void k_prep(
    const float* __restrict__ x, const float* __restrict__ xsp,
    const float* __restrict__ Wx, const float* __restrict__ Wy, const float* __restrict__ Wz,
    const float* __restrict__ W3,
    bf16* __restrict__ xb, bf16* __restrict__ xspb, bf16* __restrict__ wbf,
    bf16* __restrict__ w3b, float* __restrict__ w3bias)
{
    const int b = blockIdx.x, t = threadIdx.x;
    if (b < 1120) {
        const float* src; bf16* dst; int base;
        if (b < 512)       { src = xsp; dst = xspb; base = b * 4096; }
        else if (b < 1024) { src = x;   dst = xb;   base = (b - 512) * 4096; }
        else {
            int i = b - 1024;
            int proj = i >> 5;
            src = (proj == 0) ? Wx : (proj == 1) ? Wy : Wz;
            dst = wbf + proj * 131072;
            base = (i & 31) * 4096;
        }
        int o = base + t * 16;
#pragma unroll
        for (int u = 0; u < 4; u++) {
            float4 v = *(const float4*)(src + o + u * 4);
            bf16x4 w; w[0] = (bf16)v.x; w[1] = (bf16)v.y; w[2] = (bf16)v.z; w[3] = (bf16)v.w;
            *(bf16x4*)(dst + o + u * 4) = w;
        }
    } else {
        int nb = b - 1120;                   // 0..2063
        int n = nb * 8 + (t >> 5);           // row of W3 (i*128+k), < 16512
        int c = t & 31;
        const float* row = W3 + n * 129;
        bf16x4 w;
        w[0] = (bf16)row[4 * c + 0];
        w[1] = (bf16)row[4 * c + 1];
        w[2] = (bf16)row[4 * c + 2];
        w[3] = (bf16)row[4 * c + 3];
        *(bf16x4*)(w3b + n * 136 + 4 * c) = w;
        if (c == 0) w3bias[n] = row[128];
    }
}

// ---------------- MLP: pout[proj][m][p] = leaky_relu(A @ W^T + b) ----------------
// grid (128, 3): block = 16 m-rows; each wave owns p-tiles {wv, wv+4}.
// 384 blocks instead of 96 -> actually covers the 256 CUs.
__global__ __launch_bounds__(256) void k_mlp(
    const bf16* __restrict__ xspb, const bf16* __restrict__ xb,
    const bf16* __restrict__ wbf,
    const float* __restrict__ bx, const float* __restrict__ by, const float* __restrict__ bz,
    bf16* __restrict__ pout)
{
    const int proj = blockIdx.y;
    const bf16* A = (proj == 2) ? xb : xspb;
    const bf16* W = wbf + proj * 131072;
    const float* bias = (proj == 0) ? bx : (proj == 1) ? by : bz;
    bf16* out = pout + proj * 262144;

    const int tid = threadIdx.x;
    const int wv = tid >> 6, lane = tid & 63, quad = lane >> 4, lr = lane & 15;
    const int m0 = blockIdx.x * 16;

    f32x4 acc[2];
    acc[0] = zero4(); acc[1] = zero4();

    const bf16* brow = A + (m0 + lr) * 1024 + quad * 8;       // same rows for all 4 waves (L1-shared)
    const bf16* arow = W + (wv * 16 + lr) * 1024 + quad * 8;  // wave-private W slice

#pragma unroll 4
    for (int kw = 0; kw < 32; kw++) {
        bf16x8 bfr = *(const bf16x8*)(brow + kw * 32);
        bf16x8 a0 = *(const bf16x8*)(arow + kw * 32);
        bf16x8 a1 = *(const bf16x8*)(arow + 65536 + kw * 32); // +64 rows = (wv+4) tile
        acc[0] = MFMA(a0, bfr, acc[0]);
        acc[1] = MFMA(a1, bfr, acc[1]);
    }
#pragma unroll
    for (int s = 0; s < 2; s++) {
        int p = (wv + s * 4) * 16 + quad * 4;
        float4 bv = *(const float4*)(bias + p);
        int m = m0 + lr;
        bf16x4 o;
        float v0 = acc[s][0] + bv.x; o[0] = (bf16)(v0 > 0.f ? v0 : 0.1f * v0);
        float v1 = acc[s][1] + bv.y; o[1] = (bf16)(v1 > 0.f ? v1 : 0.1f * v1);
        float v2 = acc[s][2] + bv.z; o[2] = (bf16)(v2 > 0.f ? v2 : 0.1f * v2);
        float v3 = acc[s][3] + bv.w; o[3] = (bf16)(v3 > 0.f ? v3 : 0.1f * v3);
        *(bf16x4*)(out + m * 128 + p) = o;
    }
}

// ---------------- V[b][y][n=(i*128+k)] = sum_j yp[b,y,j]*W3[n,j] + w3bias[n] ----------------
// MFMA D[row=n][col=y]; epilogue transposes through LDS -> 16B/lane coalesced global stores.
__global__ __launch_bounds__(256, 4) void k_vgemm(
    const bf16* __restrict__ yp,     // [16][128][128]
    const bf16* __restrict__ w3b,    // [16512][136]
    const float* __restrict__ w3bias,// [16512]
    bf16* __restrict__ V)            // [16][128][16512]
{
    __shared__ bf16 Vt[128 * 136];   // [y][n_local], ld=136
    const int b = blockIdx.y;
    const int n0 = blockIdx.x * 128;
    const int tid = threadIdx.x;
    const int wv = tid >> 6, lane = tid & 63, quad = lane >> 4, lr = lane & 15;
    const int y0 = wv * 32;

    const bf16* Ab = yp + b * 16384;

    f32x4 acc[8][2];
#pragma unroll
    for (int nt = 0; nt < 8; nt++) { acc[nt][0] = zero4(); acc[nt][1] = zero4(); }

#pragma unroll
    for (int kw = 0; kw < 4; kw++) {
        bf16x8 b0 = *(const bf16x8*)(Ab + (y0 + lr) * 128 + kw * 32 + quad * 8);
        bf16x8 b1 = *(const bf16x8*)(Ab + (y0 + 16 + lr) * 128 + kw * 32 + quad * 8);
#pragma unroll
        for (int nt = 0; nt < 8; nt++) {
            bf16x8 af = *(const bf16x8*)(w3b + (n0 + nt * 16 + lr) * 136 + kw * 32 + quad * 8);
            acc[nt][0] = MFMA(af, b0, acc[nt][0]);
            acc[nt][1] = MFMA(af, b1, acc[nt][1]);
        }
    }
    // epilogue -> LDS transpose (reg r = consecutive n)
#pragma unroll
    for (int nt = 0; nt < 8; nt++) {
        int nl = nt * 16 + quad * 4;
        float4 bv = *(const float4*)(w3bias + n0 + nl);
#pragma unroll
        for (int s = 0; s < 2; s++) {
            int y = y0 + s * 16 + lr;
            bf16x4 o;
            o[0] = (bf16)(acc[nt][s][0] + bv.x);
            o[1] = (bf16)(acc[nt][s][1] + bv.y);
            o[2] = (bf16)(acc[nt][s][2] + bv.z);
            o[3] = (bf16)(acc[nt][s][3] + bv.w);
            *(bf16x4*)(&Vt[y * 136 + nl]) = o;
        }
    }
    __syncthreads();
    // coalesced write-out: 16 lanes cover one full 256B y-row
    const int yr = tid >> 4, nn = (tid & 15) * 8;
#pragma unroll
    for (int pass = 0; pass < 8; pass++) {
        int y = pass * 16 + yr;
        bf16x8 v = *(const bf16x8*)(&Vt[y * 136 + nn]);
        *(bf16x8*)(V + (b * 128 + y) * 16512 + n0 + nn) = v;
    }
}

// ---------------- per (b,y): H[z,i]=sum_k zp[z,k]*V[y,i,k]; out[b,x,y,z]=sum_i xp[x,i]*H[z,i]+H[z,128] ----------------
// __launch_bounds__(512, 4): cap VGPR at 128 so 2 blocks/CU are resident (was likely 1).
// Stage loads fully unrolled & issued up front (one exposed latency, not five).
// xp fragments deferred past GEMM1 to cut the peak live set by 16 VGPRs.
__global__ __launch_bounds__(512, 4) void k_score(
    const bf16* __restrict__ xp,    // [16][128][128]
    const bf16* __restrict__ zp,    // [16][128][128]
    const bf16* __restrict__ V,     // [16][128][16512]
    float* __restrict__ out)        // [16][128][128][128]  (b,x,y,z)
{
    __shared__ __align__(16) bf16 Vl[129 * 136];  // V tile [i][k], later H tile [z][i]
    __shared__ float Hb[128];                     // H[z][128]
    const int bi = blockIdx.x;
    const int b = bi >> 7, y = bi & 127;
    const int tid = threadIdx.x;
    const int wv = tid >> 6, lane = tid & 63, quad = lane >> 4, lr = lane & 15;
    const int r0 = wv * 16 + lr;                  // wave-owned row (z in G1, x in G2)

    const bf16* Zb = zp + b * 16384;
    const bf16* Xb = xp + b * 16384;
    const bf16* Vby = V + (b * 128 + y) * 16512;

    // ---- stage V tile: all 4+1 chunk loads issued before any use ----
    bf16x8 st[4];
#pragma unroll
    for (int u = 0; u < 4; u++) st[u] = *(const bf16x8*)(Vby + (tid + u * 512) * 8);
    bf16x8 st4;
#pragma unroll
    for (int q = 0; q < 8; q++) st4[q] = (bf16)0.f;
    if (tid < 16) st4 = *(const bf16x8*)(Vby + (2048 + tid) * 8);

    // zp fragments (independent; overlap the stage latency)
    bf16x8 bz[4];
#pragma unroll
    for (int kw = 0; kw < 4; kw++) bz[kw] = *(const bf16x8*)(Zb + r0 * 128 + kw * 32 + quad * 8);

#pragma unroll
    for (int u = 0; u < 4; u++) {
        int c = tid + u * 512;
        *(bf16x8*)(&Vl[(c >> 4) * 136 + (c & 15) * 8]) = st[u];
    }
    if (tid < 16) *(bf16x8*)(&Vl[128 * 136 + tid * 8]) = st4;   // bias row i=128
    __syncthreads();

    // ---- GEMM1: D[row=i][col=z], wave owns z in [wv*16, wv*16+16) ----
    f32x4 acc1[9];
#pragma unroll
    for (int it = 0; it < 9; it++) acc1[it] = zero4();

#pragma unroll
    for (int kw = 0; kw < 4; kw++) {
#pragma unroll
        for (int it = 0; it < 8; it++) {
            bf16x8 af = *(const bf16x8*)(&Vl[(it * 16 + lr) * 136 + kw * 32 + quad * 8]);
            acc1[it] = MFMA(af, bz[kw], acc1[it]);
        }
        bf16x8 a8;
#pragma unroll
        for (int q = 0; q < 8; q++) a8[q] = (bf16)0.f;
        if (lr == 0) a8 = *(const bf16x8*)(&Vl[128 * 136 + kw * 32 + quad * 8]);
        acc1[8] = MFMA(a8, bz[kw], acc1[8]);
    }
    __syncthreads();   // all V reads done; region can be reused for H

    // xp fragments for GEMM2 (issued now; latency hidden by H-write + barrier)
    bf16x8 bxf[4];
#pragma unroll
    for (int iw = 0; iw < 4; iw++) bxf[iw] = *(const bf16x8*)(Xb + r0 * 128 + iw * 32 + quad * 8);

    // H -> LDS (reg r = consecutive i), row stride 136
#pragma unroll
    for (int it = 0; it < 8; it++) {
        int i = it * 16 + quad * 4;
        bf16x4 o;
        o[0] = (bf16)acc1[it][0];
        o[1] = (bf16)acc1[it][1];
        o[2] = (bf16)acc1[it][2];
        o[3] = (bf16)acc1[it][3];
        *(bf16x4*)(&Vl[r0 * 136 + i]) = o;
    }
    if (quad == 0) Hb[r0] = acc1[8][0];   // bias row i=128 lives in D row 0
    __syncthreads();

    // ---- GEMM2: D[row=z][col=x], wave owns x in [wv*16, wv*16+16) ----
    f32x4 acc2[8];
#pragma unroll
    for (int zt = 0; zt < 8; zt++) acc2[zt] = zero4();

#pragma unroll
    for (int iw = 0; iw < 4; iw++) {
#pragma unroll
        for (int zt = 0; zt < 8; zt++) {
            bf16x8 ah = *(const bf16x8*)(&Vl[(zt * 16 + lr) * 136 + iw * 32 + quad * 8]);
            acc2[zt] = MFMA(ah, bxf[iw], acc2[zt]);
        }
    }
    // epilogue: cached float4 stores
#pragma unroll
    for (int zt = 0; zt < 8; zt++) {
        int zb = zt * 16 + quad * 4;
        f32x4 hb = *(const f32x4*)(&Hb[zb]);
        int xx = r0;
        f32x4 o;
        o[0] = acc2[zt][0] + hb[0];
        o[1] = acc2[zt][1] + hb[1];
        o[2] = acc2[zt][2] + hb[2];
        o[3] = acc2[zt][3] + hb[3];
        *(f32x4*)(out + (((b * 128 + xx) * 128 + y) * 128 + zb)) = o;
    }
}

extern "C" void kernel_launch(void* const* d_in, const int* in_sizes, int n_in,
                              void* d_out, int out_size, void* d_ws, size_t ws_size,
                              hipStream_t stream) {
    const float* x   = (const float*)d_in[0];
    const float* xsp = (const float*)d_in[1];
    const float* Wx  = (const float*)d_in[2];
    const float* bx  = (const float*)d_in[3];
    const float* Wy  = (const float*)d_in[4];
    const float* by  = (const float*)d_in[5];
    const float* Wz  = (const float*)d_in[6];
    const float* bz  = (const float*)d_in[7];
    const float* W3  = (const float*)d_in[8];
    float* out = (float*)d_out;

    char* ws = (char*)d_ws;
    bf16*  xspb   = (bf16*)(ws);                   // 4 MiB
    bf16*  xb     = (bf16*)(ws + 4194304);         // 4 MiB
    bf16*  wbf    = (bf16*)(ws + 8388608);         // 768 KiB
    bf16*  w3b    = (bf16*)(ws + 9175040);         // 16512*136*2 = 4.28 MiB
    bf16*  pout   = (bf16*)(ws + 13666304);        // 3*2048*128*2 = 1.5 MiB (xp,yp,zp)
    bf16*  V      = (bf16*)(ws + 15239168);        // 16*128*16512*2 = 64.5 MiB
    float* w3bias = (float*)(ws + 82872320);       // 66 KB

    k_prep<<<3184, 256, 0, stream>>>(x, xsp, Wx, Wy, Wz, W3, xb, xspb, wbf, w3b, w3bias);
    k_mlp<<<dim3(128, 3), 256, 0, stream>>>(xspb, xb, wbf, bx, by, bz, pout);
    k_vgemm<<<dim3(129, 16), 256, 0, stream>>>(pout + 262144 /*yp*/, w3b, w3bias, V);
    k_score<<<2048, 512, 0, stream>>>(pout /*xp*/, pout + 524288 /*zp*/, V, out);
}